// Round 7
// baseline (412.812 us; speedup 1.0000x reference)
//
#include <hip/hip_runtime.h>
#include <hip/hip_bf16.h>

typedef __attribute__((ext_vector_type(4))) float f32x4;
typedef __attribute__((ext_vector_type(2))) float f32x2;
typedef __attribute__((ext_vector_type(8))) short s16x8;
typedef __attribute__((ext_vector_type(4))) short s16x4;
typedef __attribute__((ext_vector_type(4))) unsigned short u16x4;

#define HW 512
#define NSLICE 128  // 16 b * 8 ch

// ---------------------------------------------------------------------------
// Kernel 1: fused conv1x1 (8->24ch) + depthwise 3x3 + head-split + transpose.
// (unchanged)
// ---------------------------------------------------------------------------
__global__ __launch_bounds__(256) void qkv_fused(
    const float* __restrict__ x, const float* __restrict__ wqkv,
    const float* __restrict__ wdw,
    __hip_bfloat16* __restrict__ qT, __hip_bfloat16* __restrict__ kT,
    __hip_bfloat16* __restrict__ vS,
    float* __restrict__ qss, float* __restrict__ kss)
{
  const int b = blockIdx.y;
  const int tile = blockIdx.x;
  const int h0 = (tile >> 4) * 32;
  const int w0 = (tile & 15) * 32;
  const int tid = threadIdx.x;

  __shared__ float ts[4][1156][2];
  __shared__ __hip_bfloat16 ot[8][32][36];
  __shared__ float colsq[4][8][32];
  __shared__ float wq_s[24][8];
  __shared__ float wd_s[24][12];

  if (tid < 192) wq_s[tid >> 3][tid & 7] = wqkv[tid];
  if (tid < 216) wd_s[tid / 9][tid % 9] = wdw[tid];

  float xr[5][8];
  #pragma unroll
  for (int p = 0; p < 5; ++p) {
    int i = tid + p * 256;
    if (i < 1156) {
      int ih = h0 - 1 + i / 34, iw = w0 - 1 + i % 34;
      bool ok = (ih >= 0 && ih < HW && iw >= 0 && iw < HW);
      #pragma unroll
      for (int c = 0; c < 8; ++c) {
        xr[p][c] = ok ? x[((size_t)(b * 8 + c) * HW + ih) * HW + iw] : 0.f;
      }
    }
  }
  __syncthreads();

  const int tw = tid & 31;
  const int th = tid >> 5;
  const int lane = tid & 63;
  const int wv = tid >> 6;

  #pragma unroll
  for (int g = 0; g < 3; ++g) {
    #pragma unroll
    for (int p = 0; p < 5; ++p) {
      int i = tid + p * 256;
      if (i < 1156) {
        #pragma unroll
        for (int op = 0; op < 4; ++op) {
          const int o = g * 8 + op * 2;
          float a0 = 0.f, a1 = 0.f;
          #pragma unroll
          for (int c = 0; c < 8; ++c) {
            a0 += xr[p][c] * wq_s[o][c];
            a1 += xr[p][c] * wq_s[o + 1][c];
          }
          ts[op][i][0] = a0;
          ts[op][i][1] = a1;
        }
      }
    }
    __syncthreads();

    #pragma unroll
    for (int op = 0; op < 4; ++op) {
      const int o = g * 8 + op * 2;
      float w2[6][3][2];
      #pragma unroll
      for (int r = 0; r < 6; ++r)
        #pragma unroll
        for (int c = 0; c < 3; ++c) {
          f32x2 v = *(const f32x2*)&ts[op][(4 * th + r) * 34 + tw + c][0];
          w2[r][c][0] = v[0];
          w2[r][c][1] = v[1];
        }
      float o0[4], o1[4];
      #pragma unroll
      for (int r = 0; r < 4; ++r) { o0[r] = 0.f; o1[r] = 0.f; }
      #pragma unroll
      for (int di = 0; di < 3; ++di)
        #pragma unroll
        for (int dj = 0; dj < 3; ++dj) {
          const float wd0 = wd_s[o][di * 3 + dj];
          const float wd1 = wd_s[o + 1][di * 3 + dj];
          #pragma unroll
          for (int r = 0; r < 4; ++r) {
            o0[r] += w2[r + di][dj][0] * wd0;
            o1[r] += w2[r + di][dj][1] * wd1;
          }
        }
      if (g < 2) {
        float s0 = o0[0] * o0[0] + o0[1] * o0[1] + o0[2] * o0[2] + o0[3] * o0[3];
        float s1 = o1[0] * o1[0] + o1[1] * o1[1] + o1[2] * o1[2] + o1[3] * o1[3];
        s0 += __shfl_xor(s0, 32);
        s1 += __shfl_xor(s1, 32);
        if (lane < 32) {
          colsq[wv][op * 2][tw] = s0;
          colsq[wv][op * 2 + 1][tw] = s1;
        }
        #pragma unroll
        for (int r = 0; r < 4; ++r) {
          ot[op * 2][tw][4 * th + r] = __float2bfloat16(o0[r]);
          ot[op * 2 + 1][tw][4 * th + r] = __float2bfloat16(o1[r]);
        }
      } else {
        #pragma unroll
        for (int r = 0; r < 4; ++r) {
          ot[op * 2][4 * th + r][tw] = __float2bfloat16(o0[r]);
          ot[op * 2 + 1][4 * th + r][tw] = __float2bfloat16(o1[r]);
        }
      }
    }
    __syncthreads();

    {
      const int rr = tid >> 3, cc = tid & 7;
      #pragma unroll
      for (int o = 0; o < 8; ++o) {
        s16x4 v = *(const s16x4*)&ot[o][rr][cc * 4];
        if (g == 0) {
          *(s16x4*)(qT + ((size_t)(b * 8 + o) * HW + w0 + rr) * HW + h0 + cc * 4) = v;
        } else if (g == 1) {
          *(s16x4*)(kT + ((size_t)(b * 8 + o) * HW + w0 + rr) * HW + h0 + cc * 4) = v;
        } else {
          *(s16x4*)(vS + ((size_t)(b * 8 + o) * HW + h0 + rr) * HW + w0 + cc * 4) = v;
        }
      }
    }
    if (g < 2) {
      const int o = tid >> 5, w = tid & 31;
      float s = colsq[0][o][w] + colsq[1][o][w] + colsq[2][o][w] + colsq[3][o][w];
      float* dst = (g == 0 ? qss : kss) + (size_t)(b * 8 + o) * HW + w0 + w;
      atomicAdd(dst, s);
    }
  }
}

// ---------------------------------------------------------------------------
// Kernel 2: per-slice attention, 8 waves, BM=64 w-rows. Depth-4 register
// pipeline with sched_barrier(0)-PINNED units: {16 MFMA + next-step loads}
// per unit; the compiler cannot sink loads to their consumers (R6 failure:
// it collapsed the rotation back to serial at VGPR=128). Occupancy is
// 1 block/CU regardless (72.4 KB dyn-LDS), so up to 256 VGPR is free.
// ---------------------------------------------------------------------------
#define LDS_P    0        // 65536: P [64][1024B] swizzled; reused as O staging
#define OFF_RMAX 65536    // [64][8] f32
#define OFF_RSUM 67584    // [64][8] f32
#define OFF_RMAXF 69632   // [64] f32
#define OFF_RSINV 69888   // [64] f32
#define OFF_SQ   70144    // [64] f32
#define OFF_SK   70400    // [512] f32
#define ATTN_LDS_SIZE 72448

// step S in [0,16): byte column = S*64 + klo within a 1024B row
#define LOADQ(AF, S) { \
    const int cbq_ = (S) * 64 + klo; \
    _Pragma("unroll") for (int m_ = 0; m_ < 4; ++m_) \
      AF[m_] = *(const s16x8*)(qs + (size_t)(m_ * 16 + arow) * 1024 + cbq_); }
#define LOADK(BF, S) { \
    const int cbk_ = (S) * 64 + klo; \
    _Pragma("unroll") for (int n_ = 0; n_ < 4; ++n_) \
      BF[n_] = *(const s16x8*)(ks + (size_t)(wv * 64 + n_ * 16 + arow) * 1024 + cbk_); }
#define LOADV(BF, S) { \
    const int cbv_ = (S) * 64 + klo; \
    _Pragma("unroll") for (int n_ = 0; n_ < 4; ++n_) \
      BF[n_] = *(const s16x8*)(vs + (size_t)(wv * 64 + n_ * 16 + arow) * 1024 + cbv_); }
#define LOADP(AF, S) { \
    const int cbp_ = (S) * 64 + klo; \
    _Pragma("unroll") for (int m_ = 0; m_ < 4; ++m_) { \
      const int row_ = m_ * 16 + arow; \
      AF[m_] = *(const s16x8*)(ldsP + row_ * 1024 + (cbp_ ^ ((row_ & 7) << 4))); } }
#define MFMA16(AF, BF, ACC) { \
    _Pragma("unroll") for (int m_ = 0; m_ < 4; ++m_) \
      _Pragma("unroll") for (int n_ = 0; n_ < 4; ++n_) \
        ACC[m_][n_] = __builtin_amdgcn_mfma_f32_16x16x32_bf16(AF[m_], BF[n_], ACC[m_][n_], 0, 0, 0); }
#define SB __builtin_amdgcn_sched_barrier(0);

__global__ __launch_bounds__(512, 1) void attn_kernel(
    const __hip_bfloat16* __restrict__ qT, const __hip_bfloat16* __restrict__ kT,
    const __hip_bfloat16* __restrict__ vS, __hip_bfloat16* __restrict__ Obuf,
    const float* __restrict__ qss, const float* __restrict__ kss,
    const float* __restrict__ temp)
{
  extern __shared__ char smem[];
  char* ldsP = smem + LDS_P;
  float* red_max  = (float*)(smem + OFF_RMAX);
  float* red_sum  = (float*)(smem + OFF_RSUM);
  float* red_maxf = (float*)(smem + OFF_RMAXF);
  float* rsinv    = (float*)(smem + OFF_RSINV);
  float* sq_l     = (float*)(smem + OFF_SQ);
  float* sk_l     = (float*)(smem + OFF_SK);

  const int tid = threadIdx.x;
  const int lane = tid & 63;
  const int wv = tid >> 6;
  const int p = blockIdx.x;
  // XCD swizzle: 8 row-blocks of one slice share an XCD (K/V L2 reuse)
  const int slice = (p & 7) + 8 * (p >> 6);
  const int rblk = (p >> 3) & 7;
  const int w0 = rblk * 64;
  const size_t sbase = (size_t)slice * HW * HW;
  const char* qs = (const char*)(qT + sbase + (size_t)w0 * HW);
  const char* ks = (const char*)(kT + sbase);
  const char* vs = (const char*)(vS + sbase);

  const int klo = (lane >> 4) << 4;   // 16B k-slot within 64B window
  const int arow = lane & 15;

  f32x4 acc[4][4];
  #pragma unroll
  for (int m = 0; m < 4; ++m)
    #pragma unroll
    for (int n = 0; n < 4; ++n) acc[m][n] = (f32x4){0.f, 0.f, 0.f, 0.f};

  // ---- phase 1: S = Q K^T, depth-4 pinned register pipeline, 16 K-steps ----
  s16x8 afA[4], bfA[4], afB[4], bfB[4], afC[4], bfC[4], afD[4], bfD[4];
  LOADQ(afA, 0) LOADK(bfA, 0)
  LOADQ(afB, 1) LOADK(bfB, 1)
  LOADQ(afC, 2) LOADK(bfC, 2)
  LOADQ(afD, 3) LOADK(bfD, 3)

  const float tmp = temp[(slice & 7) >> 1];
  if (tid < 64) sq_l[tid] = tmp / fmaxf(sqrtf(qss[(size_t)slice * HW + w0 + tid]), 1e-12f);
  sk_l[tid] = 1.f / fmaxf(sqrtf(kss[(size_t)slice * HW + tid]), 1e-12f);

  #pragma unroll
  for (int s = 0; s < 16; s += 4) {
    MFMA16(afA, bfA, acc)
    if (s + 4 < 16) { LOADQ(afA, s + 4) LOADK(bfA, s + 4) }
    SB
    MFMA16(afB, bfB, acc)
    if (s + 5 < 16) { LOADQ(afB, s + 5) LOADK(bfB, s + 5) }
    SB
    MFMA16(afC, bfC, acc)
    if (s + 6 < 16) { LOADQ(afC, s + 6) LOADK(bfC, s + 6) }
    SB
    MFMA16(afD, bfD, acc)
    if (s + 7 < 16) { LOADQ(afD, s + 7) LOADK(bfD, s + 7) }
    SB
  }
  __syncthreads();  // sq_l/sk_l visible

  // ---- softmax over v (rows w) ----
  float srow[4][4], scol[4];
  #pragma unroll
  for (int m = 0; m < 4; ++m)
    #pragma unroll
    for (int r = 0; r < 4; ++r)
      srow[m][r] = sq_l[m * 16 + ((lane >> 4) << 2) + r];
  #pragma unroll
  for (int n = 0; n < 4; ++n) scol[n] = sk_l[wv * 64 + n * 16 + (lane & 15)];

  float rmax[4][4];
  #pragma unroll
  for (int m = 0; m < 4; ++m)
    #pragma unroll
    for (int r = 0; r < 4; ++r) {
      float mx = -1e30f;
      #pragma unroll
      for (int n = 0; n < 4; ++n) {
        float v = acc[m][n][r] * srow[m][r] * scol[n];
        acc[m][n][r] = v;
        mx = fmaxf(mx, v);
      }
      mx = fmaxf(mx, __shfl_xor(mx, 1));
      mx = fmaxf(mx, __shfl_xor(mx, 2));
      mx = fmaxf(mx, __shfl_xor(mx, 4));
      mx = fmaxf(mx, __shfl_xor(mx, 8));
      rmax[m][r] = mx;
    }
  if ((lane & 15) == 0) {
    #pragma unroll
    for (int m = 0; m < 4; ++m)
      #pragma unroll
      for (int r = 0; r < 4; ++r)
        red_max[(m * 16 + ((lane >> 4) << 2) + r) * 8 + wv] = rmax[m][r];
  }
  __syncthreads();
  if (tid < 64) {
    float mx = red_max[tid * 8];
    #pragma unroll
    for (int g = 1; g < 8; ++g) mx = fmaxf(mx, red_max[tid * 8 + g]);
    red_maxf[tid] = mx;
  }
  __syncthreads();

  float gmax[4][4];
  #pragma unroll
  for (int m = 0; m < 4; ++m)
    #pragma unroll
    for (int r = 0; r < 4; ++r)
      gmax[m][r] = red_maxf[m * 16 + ((lane >> 4) << 2) + r];

  // prefetch first four V fragment sets: latency hides under the exp/P-write
  // VALU section and the P-publish barrier's vmcnt drain
  s16x8 vfA[4], vfB[4], vfC[4], vfD[4];
  LOADV(vfA, 0)
  LOADV(vfB, 1)
  LOADV(vfC, 2)
  LOADV(vfD, 3)

  float rs[4][4];
  #pragma unroll
  for (int m = 0; m < 4; ++m)
    #pragma unroll
    for (int r = 0; r < 4; ++r) rs[m][r] = 0.f;
  #pragma unroll
  for (int m = 0; m < 4; ++m)
    #pragma unroll
    for (int n = 0; n < 4; ++n)
      #pragma unroll
      for (int r = 0; r < 4; ++r) {
        int row = m * 16 + ((lane >> 4) << 2) + r;
        int col = wv * 64 + n * 16 + (lane & 15);
        float pv = __expf(acc[m][n][r] - gmax[m][r]);
        rs[m][r] += pv;
        *(__hip_bfloat16*)(ldsP + row * 1024 + ((col * 2) ^ ((row & 7) << 4))) =
            __float2bfloat16(pv);
      }
  #pragma unroll
  for (int m = 0; m < 4; ++m)
    #pragma unroll
    for (int r = 0; r < 4; ++r) {
      float s = rs[m][r];
      s += __shfl_xor(s, 1);
      s += __shfl_xor(s, 2);
      s += __shfl_xor(s, 4);
      s += __shfl_xor(s, 8);
      if ((lane & 15) == 0)
        red_sum[(m * 16 + ((lane >> 4) << 2) + r) * 8 + wv] = s;
    }
  __syncthreads();  // P + red_sum visible
  if (tid < 64) {
    float s = 0.f;
    #pragma unroll
    for (int g = 0; g < 8; ++g) s += red_sum[tid * 8 + g];
    rsinv[tid] = 1.f / s;
  }

  // ---- phase 2: O = P V, depth-4 pinned pipeline (P prefetched 1 unit,
  //      V prefetched 4 units ahead) ----
  f32x4 acc2[4][4];
  #pragma unroll
  for (int m = 0; m < 4; ++m)
    #pragma unroll
    for (int n = 0; n < 4; ++n) acc2[m][n] = (f32x4){0.f, 0.f, 0.f, 0.f};

  s16x8 pfA[4], pfB[4], pfC[4], pfD[4];
  LOADP(pfA, 0)

  #pragma unroll
  for (int s = 0; s < 16; s += 4) {
    LOADP(pfB, s + 1)
    MFMA16(pfA, vfA, acc2)
    if (s + 4 < 16) LOADV(vfA, s + 4)
    SB
    LOADP(pfC, s + 2)
    MFMA16(pfB, vfB, acc2)
    if (s + 5 < 16) LOADV(vfB, s + 5)
    SB
    LOADP(pfD, s + 3)
    MFMA16(pfC, vfC, acc2)
    if (s + 6 < 16) LOADV(vfC, s + 6)
    SB
    if (s + 4 < 16) LOADP(pfA, s + 4)
    MFMA16(pfD, vfD, acc2)
    if (s + 7 < 16) LOADV(vfD, s + 7)
    SB
  }
  __syncthreads();  // P dead; reuse its LDS for O staging

  float rinv[4][4];
  #pragma unroll
  for (int m = 0; m < 4; ++m)
    #pragma unroll
    for (int r = 0; r < 4; ++r)
      rinv[m][r] = rsinv[m * 16 + ((lane >> 4) << 2) + r];

  char* ldsO = ldsP + wv * 8192;  // per-wave [64][128B]
  #pragma unroll
  for (int m = 0; m < 4; ++m)
    #pragma unroll
    for (int n = 0; n < 4; ++n)
      #pragma unroll
      for (int r = 0; r < 4; ++r) {
        int row = m * 16 + ((lane >> 4) << 2) + r;
        int col = n * 16 + (lane & 15);
        *(__hip_bfloat16*)(ldsO + row * 128 + col * 2) =
            __float2bfloat16(acc2[m][n][r] * rinv[m][r]);
      }
  __syncthreads();
  __hip_bfloat16* ob = Obuf + sbase + (size_t)w0 * HW + wv * 64;
  #pragma unroll
  for (int it = 0; it < 8; ++it) {
    int row = it * 8 + (lane >> 3);
    int c = (lane & 7) << 4;
    s16x8 v = *(const s16x8*)(ldsO + row * 128 + c);
    *(s16x8*)((char*)ob + (size_t)row * 1024 + c) = v;
  }
}

// ---------------------------------------------------------------------------
// Kernel 3: out[b][j][h][w] = sum_o wout[j][o] * O[b][o][w][h]
// ---------------------------------------------------------------------------
__global__ __launch_bounds__(256) void proj_kernel(
    const __hip_bfloat16* __restrict__ Obuf, const float* __restrict__ wout,
    float* __restrict__ out)
{
  const int b = blockIdx.y;
  const int t = blockIdx.x;
  const int h0 = (t >> 5) * 64;
  const int w0 = (t & 31) * 16;
  const int tid = threadIdx.x;
  __shared__ float os[8][16][65];
  __shared__ float wo_s[64];
  if (tid < 64) wo_s[tid] = wout[tid];
  {
    int r = tid >> 4;
    int c4 = (tid & 15) * 4;
    #pragma unroll
    for (int o = 0; o < 8; ++o) {
      const __hip_bfloat16* p = Obuf + ((size_t)(b * 8 + o) * HW + w0 + r) * HW + h0 + c4;
      u16x4 v = *(const u16x4*)p;
      #pragma unroll
      for (int i = 0; i < 4; ++i)
        os[o][r][c4 + i] = __uint_as_float((unsigned)v[i] << 16);
    }
  }
  __syncthreads();
  const int w = tid & 15;
  #pragma unroll
  for (int ih = 0; ih < 4; ++ih) {
    int h = ih * 16 + (tid >> 4);
    float ov[8];
    #pragma unroll
    for (int o = 0; o < 8; ++o) ov[o] = os[o][w][h];
    #pragma unroll
    for (int jo = 0; jo < 8; ++jo) {
      float a = 0.f;
      #pragma unroll
      for (int o = 0; o < 8; ++o) a += ov[o] * wo_s[jo * 8 + o];
      out[((size_t)(b * 8 + jo) * HW + h0 + h) * HW + w0 + w] = a;
    }
  }
}

extern "C" void kernel_launch(void* const* d_in, const int* in_sizes, int n_in,
                              void* d_out, int out_size, void* d_ws, size_t ws_size,
                              hipStream_t stream) {
  (void)in_sizes; (void)n_in; (void)out_size; (void)ws_size;
  const float* x    = (const float*)d_in[0];
  const float* wqkv = (const float*)d_in[1];
  const float* wdw  = (const float*)d_in[2];
  const float* wout = (const float*)d_in[3];
  const float* temp = (const float*)d_in[4];
  float* out = (float*)d_out;

  char* ws = (char*)d_ws;
  const size_t plane = (size_t)NSLICE * HW * HW * 2;  // 64 MiB bf16 plane
  __hip_bfloat16* qT = (__hip_bfloat16*)(ws);
  __hip_bfloat16* kT = (__hip_bfloat16*)(ws + plane);
  __hip_bfloat16* vS = (__hip_bfloat16*)(ws + 2 * plane);
  __hip_bfloat16* Ob = (__hip_bfloat16*)(ws + 3 * plane);
  float* qss = (float*)(ws + 4 * plane);
  float* kss = (float*)(ws + 4 * plane + (size_t)NSLICE * HW * 4);

  hipMemsetAsync(qss, 0, 2 * (size_t)NSLICE * HW * 4, stream);
  qkv_fused<<<dim3(256, 16), 256, 0, stream>>>(x, wqkv, wdw, qT, kT, vS, qss, kss);
  hipFuncSetAttribute((const void*)attn_kernel,
                      hipFuncAttributeMaxDynamicSharedMemorySize, ATTN_LDS_SIZE);
  attn_kernel<<<dim3(1024), 512, ATTN_LDS_SIZE, stream>>>(qT, kT, vS, Ob, qss, kss, temp);
  proj_kernel<<<dim3(256, 16), 256, 0, stream>>>(Ob, wout, out);
}

// Round 9
// 373.607 us; speedup vs baseline: 1.1049x; 1.1049x over previous
//
#include <hip/hip_runtime.h>
#include <hip/hip_bf16.h>

typedef __attribute__((ext_vector_type(4))) float f32x4;
typedef __attribute__((ext_vector_type(2))) float f32x2;
typedef __attribute__((ext_vector_type(8))) short s16x8;
typedef __attribute__((ext_vector_type(4))) short s16x4;
typedef __attribute__((ext_vector_type(4))) unsigned short u16x4;

#define HW 512
#define NSLICE 128  // 16 b * 8 ch

// ---------------------------------------------------------------------------
// Kernel 1: fused conv1x1 (8->24ch) + depthwise 3x3 + head-split.
// NEW: q/k/v written in h-chunk-tiled layout [slice][chn][row][32] (row
// stride 64B) so attention fragment loads are contiguous-1KB per instruction
// (old layout: 16 lanes @ 1KB stride -> L2 channel camping).
//   qT/kT: chn = h/32, row = w   (QK^T contracts over h)
//   vS   : chn = v/32, row = h   (PV contracts over v; V consumed as [h][v])
// ---------------------------------------------------------------------------
__global__ __launch_bounds__(256) void qkv_fused(
    const float* __restrict__ x, const float* __restrict__ wqkv,
    const float* __restrict__ wdw,
    __hip_bfloat16* __restrict__ qT, __hip_bfloat16* __restrict__ kT,
    __hip_bfloat16* __restrict__ vS,
    float* __restrict__ qss, float* __restrict__ kss)
{
  const int b = blockIdx.y;
  const int tile = blockIdx.x;
  const int h0 = (tile >> 4) * 32;
  const int w0 = (tile & 15) * 32;
  const int tid = threadIdx.x;

  __shared__ float ts[4][1156][2];
  __shared__ __hip_bfloat16 ot[8][32][36];
  __shared__ float colsq[4][8][32];
  __shared__ float wq_s[24][8];
  __shared__ float wd_s[24][12];

  if (tid < 192) wq_s[tid >> 3][tid & 7] = wqkv[tid];
  if (tid < 216) wd_s[tid / 9][tid % 9] = wdw[tid];

  float xr[5][8];
  #pragma unroll
  for (int p = 0; p < 5; ++p) {
    int i = tid + p * 256;
    if (i < 1156) {
      int ih = h0 - 1 + i / 34, iw = w0 - 1 + i % 34;
      bool ok = (ih >= 0 && ih < HW && iw >= 0 && iw < HW);
      #pragma unroll
      for (int c = 0; c < 8; ++c) {
        xr[p][c] = ok ? x[((size_t)(b * 8 + c) * HW + ih) * HW + iw] : 0.f;
      }
    }
  }
  __syncthreads();

  const int tw = tid & 31;
  const int th = tid >> 5;
  const int lane = tid & 63;
  const int wv = tid >> 6;

  #pragma unroll
  for (int g = 0; g < 3; ++g) {
    #pragma unroll
    for (int p = 0; p < 5; ++p) {
      int i = tid + p * 256;
      if (i < 1156) {
        #pragma unroll
        for (int op = 0; op < 4; ++op) {
          const int o = g * 8 + op * 2;
          float a0 = 0.f, a1 = 0.f;
          #pragma unroll
          for (int c = 0; c < 8; ++c) {
            a0 += xr[p][c] * wq_s[o][c];
            a1 += xr[p][c] * wq_s[o + 1][c];
          }
          ts[op][i][0] = a0;
          ts[op][i][1] = a1;
        }
      }
    }
    __syncthreads();

    #pragma unroll
    for (int op = 0; op < 4; ++op) {
      const int o = g * 8 + op * 2;
      float w2[6][3][2];
      #pragma unroll
      for (int r = 0; r < 6; ++r)
        #pragma unroll
        for (int c = 0; c < 3; ++c) {
          f32x2 v = *(const f32x2*)&ts[op][(4 * th + r) * 34 + tw + c][0];
          w2[r][c][0] = v[0];
          w2[r][c][1] = v[1];
        }
      float o0[4], o1[4];
      #pragma unroll
      for (int r = 0; r < 4; ++r) { o0[r] = 0.f; o1[r] = 0.f; }
      #pragma unroll
      for (int di = 0; di < 3; ++di)
        #pragma unroll
        for (int dj = 0; dj < 3; ++dj) {
          const float wd0 = wd_s[o][di * 3 + dj];
          const float wd1 = wd_s[o + 1][di * 3 + dj];
          #pragma unroll
          for (int r = 0; r < 4; ++r) {
            o0[r] += w2[r + di][dj][0] * wd0;
            o1[r] += w2[r + di][dj][1] * wd1;
          }
        }
      if (g < 2) {
        float s0 = o0[0] * o0[0] + o0[1] * o0[1] + o0[2] * o0[2] + o0[3] * o0[3];
        float s1 = o1[0] * o1[0] + o1[1] * o1[1] + o1[2] * o1[2] + o1[3] * o1[3];
        s0 += __shfl_xor(s0, 32);
        s1 += __shfl_xor(s1, 32);
        if (lane < 32) {
          colsq[wv][op * 2][tw] = s0;
          colsq[wv][op * 2 + 1][tw] = s1;
        }
        // stage transposed [o][w][h-within-chunk]
        #pragma unroll
        for (int r = 0; r < 4; ++r) {
          ot[op * 2][tw][4 * th + r] = __float2bfloat16(o0[r]);
          ot[op * 2 + 1][tw][4 * th + r] = __float2bfloat16(o1[r]);
        }
      } else {
        // stage natural [o][h][w-within-chunk]
        #pragma unroll
        for (int r = 0; r < 4; ++r) {
          ot[op * 2][4 * th + r][tw] = __float2bfloat16(o0[r]);
          ot[op * 2 + 1][4 * th + r][tw] = __float2bfloat16(o1[r]);
        }
      }
    }
    __syncthreads();

    {
      const int rr = tid >> 3, cc = tid & 7;
      #pragma unroll
      for (int o = 0; o < 8; ++o) {
        s16x4 v = *(const s16x4*)&ot[o][rr][cc * 4];
        const size_t sb = (size_t)(b * 8 + o) * HW * HW;
        if (g == 0) {
          // qT'[slice][h0/32][w0+rr][cc*4..]
          *(s16x4*)(qT + sb + (size_t)(h0 >> 5) * HW * 32 + (size_t)(w0 + rr) * 32 + cc * 4) = v;
        } else if (g == 1) {
          *(s16x4*)(kT + sb + (size_t)(h0 >> 5) * HW * 32 + (size_t)(w0 + rr) * 32 + cc * 4) = v;
        } else {
          // vS'[slice][w0/32][h0+rr][cc*4..]  (chunk dim = v = w spatial)
          *(s16x4*)(vS + sb + (size_t)(w0 >> 5) * HW * 32 + (size_t)(h0 + rr) * 32 + cc * 4) = v;
        }
      }
    }
    if (g < 2) {
      const int o = tid >> 5, w = tid & 31;
      float s = colsq[0][o][w] + colsq[1][o][w] + colsq[2][o][w] + colsq[3][o][w];
      float* dst = (g == 0 ? qss : kss) + (size_t)(b * 8 + o) * HW + w0 + w;
      atomicAdd(dst, s);
    }
  }
}

// ---------------------------------------------------------------------------
// Kernel 2: per-slice attention (R7-proven structure: 8 waves, BM=64, direct
// global->reg fragments, LDS only for P + reductions). ONLY CHANGE vs R7:
// fragment loads address the h-chunk-tiled layout -> each load instruction
// reads one contiguous 1KB block (64 lanes x 16B) instead of 16 lines at
// 1KB stride (L2 channel camping fix).
// ---------------------------------------------------------------------------
#define LDS_P    0        // 65536: P [64][1024B] swizzled; reused as O staging
#define OFF_RMAX 65536    // [64][8] f32
#define OFF_RSUM 67584    // [64][8] f32
#define OFF_RMAXF 69632   // [64] f32
#define OFF_RSINV 69888   // [64] f32
#define OFF_SQ   70144    // [64] f32
#define OFF_SK   70400    // [512] f32
#define ATTN_LDS_SIZE 72448

// chunk S in [0,16): base byte = S*32768; row stride 64B; klo = 16B sub-slot
#define LOADQ(AF, S) { \
    const size_t cq_ = (size_t)(S) * 32768 + klo; \
    _Pragma("unroll") for (int m_ = 0; m_ < 4; ++m_) \
      AF[m_] = *(const s16x8*)(qs + cq_ + (size_t)(w0 + m_ * 16 + arow) * 64); }
#define LOADK(BF, S) { \
    const size_t ck_ = (size_t)(S) * 32768 + klo; \
    _Pragma("unroll") for (int n_ = 0; n_ < 4; ++n_) \
      BF[n_] = *(const s16x8*)(ks + ck_ + (size_t)(wv * 64 + n_ * 16 + arow) * 64); }
#define LOADV(BF, S) { \
    const size_t cv_ = (size_t)(S) * 32768 + klo; \
    _Pragma("unroll") for (int n_ = 0; n_ < 4; ++n_) \
      BF[n_] = *(const s16x8*)(vs + cv_ + (size_t)(wv * 64 + n_ * 16 + arow) * 64); }
#define LOADP(AF, S) { \
    const int cbp_ = (S) * 64 + klo; \
    _Pragma("unroll") for (int m_ = 0; m_ < 4; ++m_) { \
      const int row_ = m_ * 16 + arow; \
      AF[m_] = *(const s16x8*)(ldsP + row_ * 1024 + (cbp_ ^ ((row_ & 7) << 4))); } }
#define MFMA16(AF, BF, ACC) { \
    _Pragma("unroll") for (int m_ = 0; m_ < 4; ++m_) \
      _Pragma("unroll") for (int n_ = 0; n_ < 4; ++n_) \
        ACC[m_][n_] = __builtin_amdgcn_mfma_f32_16x16x32_bf16(AF[m_], BF[n_], ACC[m_][n_], 0, 0, 0); }

__global__ __launch_bounds__(512, 1) void attn_kernel(
    const __hip_bfloat16* __restrict__ qT, const __hip_bfloat16* __restrict__ kT,
    const __hip_bfloat16* __restrict__ vS, __hip_bfloat16* __restrict__ Obuf,
    const float* __restrict__ qss, const float* __restrict__ kss,
    const float* __restrict__ temp)
{
  extern __shared__ char smem[];
  char* ldsP = smem + LDS_P;
  float* red_max  = (float*)(smem + OFF_RMAX);
  float* red_sum  = (float*)(smem + OFF_RSUM);
  float* red_maxf = (float*)(smem + OFF_RMAXF);
  float* rsinv    = (float*)(smem + OFF_RSINV);
  float* sq_l     = (float*)(smem + OFF_SQ);
  float* sk_l     = (float*)(smem + OFF_SK);

  const int tid = threadIdx.x;
  const int lane = tid & 63;
  const int wv = tid >> 6;
  const int p = blockIdx.x;
  // XCD swizzle: 8 row-blocks of one slice share an XCD (K/V L2 reuse)
  const int slice = (p & 7) + 8 * (p >> 6);
  const int rblk = (p >> 3) & 7;
  const int w0 = rblk * 64;
  const size_t sbase = (size_t)slice * HW * HW;
  const char* qs = (const char*)(qT + sbase);
  const char* ks = (const char*)(kT + sbase);
  const char* vs = (const char*)(vS + sbase);

  const int klo = (lane >> 4) << 4;   // 16B k-slot within 64B row
  const int arow = lane & 15;

  f32x4 acc[4][4];
  #pragma unroll
  for (int m = 0; m < 4; ++m)
    #pragma unroll
    for (int n = 0; n < 4; ++n) acc[m][n] = (f32x4){0.f, 0.f, 0.f, 0.f};

  const float tmp = temp[(slice & 7) >> 1];
  if (tid < 64) sq_l[tid] = tmp / fmaxf(sqrtf(qss[(size_t)slice * HW + w0 + tid]), 1e-12f);
  sk_l[tid] = 1.f / fmaxf(sqrtf(kss[(size_t)slice * HW + tid]), 1e-12f);

  // ---- phase 1: S = Q K^T (contraction over h), 16 chunk-steps ----
  for (int chn = 0; chn < 16; ++chn) {
    s16x8 af[4], bf[4];
    LOADQ(af, chn)
    LOADK(bf, chn)
    MFMA16(af, bf, acc)
  }
  __syncthreads();  // sq_l/sk_l visible

  // ---- softmax over v (rows w) ----
  float srow[4][4], scol[4];
  #pragma unroll
  for (int m = 0; m < 4; ++m)
    #pragma unroll
    for (int r = 0; r < 4; ++r)
      srow[m][r] = sq_l[m * 16 + ((lane >> 4) << 2) + r];
  #pragma unroll
  for (int n = 0; n < 4; ++n) scol[n] = sk_l[wv * 64 + n * 16 + (lane & 15)];

  float rmax[4][4];
  #pragma unroll
  for (int m = 0; m < 4; ++m)
    #pragma unroll
    for (int r = 0; r < 4; ++r) {
      float mx = -1e30f;
      #pragma unroll
      for (int n = 0; n < 4; ++n) {
        float v = acc[m][n][r] * srow[m][r] * scol[n];
        acc[m][n][r] = v;
        mx = fmaxf(mx, v);
      }
      mx = fmaxf(mx, __shfl_xor(mx, 1));
      mx = fmaxf(mx, __shfl_xor(mx, 2));
      mx = fmaxf(mx, __shfl_xor(mx, 4));
      mx = fmaxf(mx, __shfl_xor(mx, 8));
      rmax[m][r] = mx;
    }
  if ((lane & 15) == 0) {
    #pragma unroll
    for (int m = 0; m < 4; ++m)
      #pragma unroll
      for (int r = 0; r < 4; ++r)
        red_max[(m * 16 + ((lane >> 4) << 2) + r) * 8 + wv] = rmax[m][r];
  }
  __syncthreads();
  if (tid < 64) {
    float mx = red_max[tid * 8];
    #pragma unroll
    for (int g = 1; g < 8; ++g) mx = fmaxf(mx, red_max[tid * 8 + g]);
    red_maxf[tid] = mx;
  }
  __syncthreads();

  float gmax[4][4];
  #pragma unroll
  for (int m = 0; m < 4; ++m)
    #pragma unroll
    for (int r = 0; r < 4; ++r)
      gmax[m][r] = red_maxf[m * 16 + ((lane >> 4) << 2) + r];

  float rs[4][4];
  #pragma unroll
  for (int m = 0; m < 4; ++m)
    #pragma unroll
    for (int r = 0; r < 4; ++r) rs[m][r] = 0.f;
  #pragma unroll
  for (int m = 0; m < 4; ++m)
    #pragma unroll
    for (int n = 0; n < 4; ++n)
      #pragma unroll
      for (int r = 0; r < 4; ++r) {
        int row = m * 16 + ((lane >> 4) << 2) + r;
        int col = wv * 64 + n * 16 + (lane & 15);
        float pv = __expf(acc[m][n][r] - gmax[m][r]);
        rs[m][r] += pv;
        *(__hip_bfloat16*)(ldsP + row * 1024 + ((col * 2) ^ ((row & 7) << 4))) =
            __float2bfloat16(pv);
      }
  #pragma unroll
  for (int m = 0; m < 4; ++m)
    #pragma unroll
    for (int r = 0; r < 4; ++r) {
      float s = rs[m][r];
      s += __shfl_xor(s, 1);
      s += __shfl_xor(s, 2);
      s += __shfl_xor(s, 4);
      s += __shfl_xor(s, 8);
      if ((lane & 15) == 0)
        red_sum[(m * 16 + ((lane >> 4) << 2) + r) * 8 + wv] = s;
    }
  __syncthreads();  // P + red_sum visible
  if (tid < 64) {
    float s = 0.f;
    #pragma unroll
    for (int g = 0; g < 8; ++g) s += red_sum[tid * 8 + g];
    rsinv[tid] = 1.f / s;
  }

  // ---- phase 2: O = P V (contraction over v); P from LDS, V direct ----
  f32x4 acc2[4][4];
  #pragma unroll
  for (int m = 0; m < 4; ++m)
    #pragma unroll
    for (int n = 0; n < 4; ++n) acc2[m][n] = (f32x4){0.f, 0.f, 0.f, 0.f};

  for (int chn = 0; chn < 16; ++chn) {
    s16x8 af[4], bf[4];
    LOADP(af, chn)
    LOADV(bf, chn)
    MFMA16(af, bf, acc2)
  }
  __syncthreads();  // P dead; reuse its LDS for O staging

  float rinv[4][4];
  #pragma unroll
  for (int m = 0; m < 4; ++m)
    #pragma unroll
    for (int r = 0; r < 4; ++r)
      rinv[m][r] = rsinv[m * 16 + ((lane >> 4) << 2) + r];

  char* ldsO = ldsP + wv * 8192;  // per-wave [64][128B]
  #pragma unroll
  for (int m = 0; m < 4; ++m)
    #pragma unroll
    for (int n = 0; n < 4; ++n)
      #pragma unroll
      for (int r = 0; r < 4; ++r) {
        int row = m * 16 + ((lane >> 4) << 2) + r;
        int col = n * 16 + (lane & 15);
        *(__hip_bfloat16*)(ldsO + row * 128 + col * 2) =
            __float2bfloat16(acc2[m][n][r] * rinv[m][r]);
      }
  __syncthreads();
  __hip_bfloat16* ob = Obuf + sbase + (size_t)w0 * HW + wv * 64;
  #pragma unroll
  for (int it = 0; it < 8; ++it) {
    int row = it * 8 + (lane >> 3);
    int c = (lane & 7) << 4;
    s16x8 v = *(const s16x8*)(ldsO + row * 128 + c);
    *(s16x8*)((char*)ob + (size_t)row * 1024 + c) = v;
  }
}

// ---------------------------------------------------------------------------
// Kernel 3: out[b][j][h][w] = sum_o wout[j][o] * O[b][o][w][h]
// ---------------------------------------------------------------------------
__global__ __launch_bounds__(256) void proj_kernel(
    const __hip_bfloat16* __restrict__ Obuf, const float* __restrict__ wout,
    float* __restrict__ out)
{
  const int b = blockIdx.y;
  const int t = blockIdx.x;
  const int h0 = (t >> 5) * 64;
  const int w0 = (t & 31) * 16;
  const int tid = threadIdx.x;
  __shared__ float os[8][16][65];
  __shared__ float wo_s[64];
  if (tid < 64) wo_s[tid] = wout[tid];
  {
    int r = tid >> 4;
    int c4 = (tid & 15) * 4;
    #pragma unroll
    for (int o = 0; o < 8; ++o) {
      const __hip_bfloat16* p = Obuf + ((size_t)(b * 8 + o) * HW + w0 + r) * HW + h0 + c4;
      u16x4 v = *(const u16x4*)p;
      #pragma unroll
      for (int i = 0; i < 4; ++i)
        os[o][r][c4 + i] = __uint_as_float((unsigned)v[i] << 16);
    }
  }
  __syncthreads();
  const int w = tid & 15;
  #pragma unroll
  for (int ih = 0; ih < 4; ++ih) {
    int h = ih * 16 + (tid >> 4);
    float ov[8];
    #pragma unroll
    for (int o = 0; o < 8; ++o) ov[o] = os[o][w][h];
    #pragma unroll
    for (int jo = 0; jo < 8; ++jo) {
      float a = 0.f;
      #pragma unroll
      for (int o = 0; o < 8; ++o) a += ov[o] * wo_s[jo * 8 + o];
      out[((size_t)(b * 8 + jo) * HW + h0 + h) * HW + w0 + w] = a;
    }
  }
}

extern "C" void kernel_launch(void* const* d_in, const int* in_sizes, int n_in,
                              void* d_out, int out_size, void* d_ws, size_t ws_size,
                              hipStream_t stream) {
  (void)in_sizes; (void)n_in; (void)out_size; (void)ws_size;
  const float* x    = (const float*)d_in[0];
  const float* wqkv = (const float*)d_in[1];
  const float* wdw  = (const float*)d_in[2];
  const float* wout = (const float*)d_in[3];
  const float* temp = (const float*)d_in[4];
  float* out = (float*)d_out;

  char* ws = (char*)d_ws;
  const size_t plane = (size_t)NSLICE * HW * HW * 2;  // 64 MiB bf16 plane
  __hip_bfloat16* qT = (__hip_bfloat16*)(ws);
  __hip_bfloat16* kT = (__hip_bfloat16*)(ws + plane);
  __hip_bfloat16* vS = (__hip_bfloat16*)(ws + 2 * plane);
  __hip_bfloat16* Ob = (__hip_bfloat16*)(ws + 3 * plane);
  float* qss = (float*)(ws + 4 * plane);
  float* kss = (float*)(ws + 4 * plane + (size_t)NSLICE * HW * 4);

  hipMemsetAsync(qss, 0, 2 * (size_t)NSLICE * HW * 4, stream);
  qkv_fused<<<dim3(256, 16), 256, 0, stream>>>(x, wqkv, wdw, qT, kT, vS, qss, kss);
  hipFuncSetAttribute((const void*)attn_kernel,
                      hipFuncAttributeMaxDynamicSharedMemorySize, ATTN_LDS_SIZE);
  attn_kernel<<<dim3(1024), 512, ATTN_LDS_SIZE, stream>>>(qT, kT, vS, Ob, qss, kss, temp);
  proj_kernel<<<dim3(256, 16), 256, 0, stream>>>(Ob, wout, out);
}

// Round 10
// 341.623 us; speedup vs baseline: 1.2084x; 1.0936x over previous
//
#include <hip/hip_runtime.h>
#include <hip/hip_bf16.h>

typedef __attribute__((ext_vector_type(4))) float f32x4;
typedef __attribute__((ext_vector_type(2))) float f32x2;
typedef __attribute__((ext_vector_type(8))) short s16x8;
typedef __attribute__((ext_vector_type(4))) short s16x4;
typedef __attribute__((ext_vector_type(4))) unsigned short u16x4;

#define HW 512
#define NSLICE 128  // 16 b * 8 ch

// ---------------------------------------------------------------------------
// Kernel 1: fused conv1x1 (8->24ch) + depthwise 3x3 + head-split.
// Chunked layout (R9): [slice][chn][row][32 bf16], row stride 64B.
//   qT/kT: chn = h/32, row = w ; vS: chn = v/32, row = h.
// ---------------------------------------------------------------------------
__global__ __launch_bounds__(256) void qkv_fused(
    const float* __restrict__ x, const float* __restrict__ wqkv,
    const float* __restrict__ wdw,
    __hip_bfloat16* __restrict__ qT, __hip_bfloat16* __restrict__ kT,
    __hip_bfloat16* __restrict__ vS,
    float* __restrict__ qss, float* __restrict__ kss)
{
  const int b = blockIdx.y;
  const int tile = blockIdx.x;
  const int h0 = (tile >> 4) * 32;
  const int w0 = (tile & 15) * 32;
  const int tid = threadIdx.x;

  __shared__ float ts[4][1156][2];
  __shared__ __hip_bfloat16 ot[8][32][36];
  __shared__ float colsq[4][8][32];
  __shared__ float wq_s[24][8];
  __shared__ float wd_s[24][12];

  if (tid < 192) wq_s[tid >> 3][tid & 7] = wqkv[tid];
  if (tid < 216) wd_s[tid / 9][tid % 9] = wdw[tid];

  float xr[5][8];
  #pragma unroll
  for (int p = 0; p < 5; ++p) {
    int i = tid + p * 256;
    if (i < 1156) {
      int ih = h0 - 1 + i / 34, iw = w0 - 1 + i % 34;
      bool ok = (ih >= 0 && ih < HW && iw >= 0 && iw < HW);
      #pragma unroll
      for (int c = 0; c < 8; ++c) {
        xr[p][c] = ok ? x[((size_t)(b * 8 + c) * HW + ih) * HW + iw] : 0.f;
      }
    }
  }
  __syncthreads();

  const int tw = tid & 31;
  const int th = tid >> 5;
  const int lane = tid & 63;
  const int wv = tid >> 6;

  #pragma unroll
  for (int g = 0; g < 3; ++g) {
    #pragma unroll
    for (int p = 0; p < 5; ++p) {
      int i = tid + p * 256;
      if (i < 1156) {
        #pragma unroll
        for (int op = 0; op < 4; ++op) {
          const int o = g * 8 + op * 2;
          float a0 = 0.f, a1 = 0.f;
          #pragma unroll
          for (int c = 0; c < 8; ++c) {
            a0 += xr[p][c] * wq_s[o][c];
            a1 += xr[p][c] * wq_s[o + 1][c];
          }
          ts[op][i][0] = a0;
          ts[op][i][1] = a1;
        }
      }
    }
    __syncthreads();

    #pragma unroll
    for (int op = 0; op < 4; ++op) {
      const int o = g * 8 + op * 2;
      float w2[6][3][2];
      #pragma unroll
      for (int r = 0; r < 6; ++r)
        #pragma unroll
        for (int c = 0; c < 3; ++c) {
          f32x2 v = *(const f32x2*)&ts[op][(4 * th + r) * 34 + tw + c][0];
          w2[r][c][0] = v[0];
          w2[r][c][1] = v[1];
        }
      float o0[4], o1[4];
      #pragma unroll
      for (int r = 0; r < 4; ++r) { o0[r] = 0.f; o1[r] = 0.f; }
      #pragma unroll
      for (int di = 0; di < 3; ++di)
        #pragma unroll
        for (int dj = 0; dj < 3; ++dj) {
          const float wd0 = wd_s[o][di * 3 + dj];
          const float wd1 = wd_s[o + 1][di * 3 + dj];
          #pragma unroll
          for (int r = 0; r < 4; ++r) {
            o0[r] += w2[r + di][dj][0] * wd0;
            o1[r] += w2[r + di][dj][1] * wd1;
          }
        }
      if (g < 2) {
        float s0 = o0[0] * o0[0] + o0[1] * o0[1] + o0[2] * o0[2] + o0[3] * o0[3];
        float s1 = o1[0] * o1[0] + o1[1] * o1[1] + o1[2] * o1[2] + o1[3] * o1[3];
        s0 += __shfl_xor(s0, 32);
        s1 += __shfl_xor(s1, 32);
        if (lane < 32) {
          colsq[wv][op * 2][tw] = s0;
          colsq[wv][op * 2 + 1][tw] = s1;
        }
        #pragma unroll
        for (int r = 0; r < 4; ++r) {
          ot[op * 2][tw][4 * th + r] = __float2bfloat16(o0[r]);
          ot[op * 2 + 1][tw][4 * th + r] = __float2bfloat16(o1[r]);
        }
      } else {
        #pragma unroll
        for (int r = 0; r < 4; ++r) {
          ot[op * 2][4 * th + r][tw] = __float2bfloat16(o0[r]);
          ot[op * 2 + 1][4 * th + r][tw] = __float2bfloat16(o1[r]);
        }
      }
    }
    __syncthreads();

    {
      const int rr = tid >> 3, cc = tid & 7;
      #pragma unroll
      for (int o = 0; o < 8; ++o) {
        s16x4 v = *(const s16x4*)&ot[o][rr][cc * 4];
        const size_t sb = (size_t)(b * 8 + o) * HW * HW;
        if (g == 0) {
          *(s16x4*)(qT + sb + (size_t)(h0 >> 5) * HW * 32 + (size_t)(w0 + rr) * 32 + cc * 4) = v;
        } else if (g == 1) {
          *(s16x4*)(kT + sb + (size_t)(h0 >> 5) * HW * 32 + (size_t)(w0 + rr) * 32 + cc * 4) = v;
        } else {
          *(s16x4*)(vS + sb + (size_t)(w0 >> 5) * HW * 32 + (size_t)(h0 + rr) * 32 + cc * 4) = v;
        }
      }
    }
    if (g < 2) {
      const int o = tid >> 5, w = tid & 31;
      float s = colsq[0][o][w] + colsq[1][o][w] + colsq[2][o][w] + colsq[3][o][w];
      float* dst = (g == 0 ? qss : kss) + (size_t)(b * 8 + o) * HW + w0 + w;
      atomicAdd(dst, s);
    }
  }
}

// ---------------------------------------------------------------------------
// Kernel 2: per-slice attention, R9 structure (8 waves, BM=64, chunked
// layout). NEW: fragment loads are asm-volatile global_load_dwordx4 with
// counted s_waitcnt vmcnt(N)+sched_barrier(0) — RA cannot collapse the 4
// in-flight sets (R5-R7 failure mode), asm order is pinned. AITER-style
// steady state: {vmcnt(24) -> 16 MFMA -> issue next 8 loads} per phase.
// ---------------------------------------------------------------------------
#define LDS_P    0        // 65536: P [64][1024B] swizzled; reused as O staging
#define OFF_RMAX 65536    // [64][8] f32
#define OFF_RSUM 67584    // [64][8] f32
#define OFF_RMAXF 69632   // [64] f32
#define OFF_RSINV 69888   // [64] f32
#define OFF_SQ   70144    // [64] f32
#define OFF_SK   70400    // [512] f32
#define ATTN_LDS_SIZE 72448

// 4 fragment loads: base(SGPR pair) + voff(VGPR) + imm row-block offset
#define GL4(D, VOFF, BASE) \
  asm volatile("global_load_dwordx4 %0, %1, %2 offset:0"    : "=v"(D[0]) : "v"(VOFF), "s"(BASE)); \
  asm volatile("global_load_dwordx4 %0, %1, %2 offset:1024" : "=v"(D[1]) : "v"(VOFF), "s"(BASE)); \
  asm volatile("global_load_dwordx4 %0, %1, %2 offset:2048" : "=v"(D[2]) : "v"(VOFF), "s"(BASE)); \
  asm volatile("global_load_dwordx4 %0, %1, %2 offset:3072" : "=v"(D[3]) : "v"(VOFF), "s"(BASE));

#define LOADSET1(AF, BF, CHN) { \
  const char* bq_ = qs + (size_t)(CHN) * 32768; \
  const char* bk_ = ks + (size_t)(CHN) * 32768; \
  GL4(AF, voffQ, bq_) \
  GL4(BF, voffK, bk_) }

#define LOADSETV(VF, CHN) { \
  const char* bv_ = vs + (size_t)(CHN) * 32768; \
  GL4(VF, voffK, bv_) }

#define WAITV(N) \
  asm volatile("s_waitcnt vmcnt(" #N ")"); \
  __builtin_amdgcn_sched_barrier(0);

#define LOADP(AF, S) { \
    const int cbp_ = (S) * 64 + klo; \
    _Pragma("unroll") for (int m_ = 0; m_ < 4; ++m_) { \
      const int row_ = m_ * 16 + arow; \
      AF[m_] = *(const s16x8*)(ldsP + row_ * 1024 + (cbp_ ^ ((row_ & 7) << 4))); } }
#define MFMA16(AF, BF, ACC) { \
    _Pragma("unroll") for (int m_ = 0; m_ < 4; ++m_) \
      _Pragma("unroll") for (int n_ = 0; n_ < 4; ++n_) \
        ACC[m_][n_] = __builtin_amdgcn_mfma_f32_16x16x32_bf16(AF[m_], BF[n_], ACC[m_][n_], 0, 0, 0); }

__global__ __launch_bounds__(512, 1) void attn_kernel(
    const __hip_bfloat16* __restrict__ qT, const __hip_bfloat16* __restrict__ kT,
    const __hip_bfloat16* __restrict__ vS, __hip_bfloat16* __restrict__ Obuf,
    const float* __restrict__ qss, const float* __restrict__ kss,
    const float* __restrict__ temp)
{
  extern __shared__ char smem[];
  char* ldsP = smem + LDS_P;
  float* red_max  = (float*)(smem + OFF_RMAX);
  float* red_sum  = (float*)(smem + OFF_RSUM);
  float* red_maxf = (float*)(smem + OFF_RMAXF);
  float* rsinv    = (float*)(smem + OFF_RSINV);
  float* sq_l     = (float*)(smem + OFF_SQ);
  float* sk_l     = (float*)(smem + OFF_SK);

  const int tid = threadIdx.x;
  const int lane = tid & 63;
  const int wv = tid >> 6;
  const int p = blockIdx.x;
  // XCD swizzle: 8 row-blocks of one slice share an XCD (K/V L2 reuse)
  const int slice = (p & 7) + 8 * (p >> 6);
  const int rblk = (p >> 3) & 7;
  const int w0 = rblk * 64;
  const size_t sbase = (size_t)slice * HW * HW;
  const char* qs = (const char*)(qT + sbase);
  const char* ks = (const char*)(kT + sbase);
  const char* vs = (const char*)(vS + sbase);

  const int klo = (lane >> 4) << 4;   // 16B k-slot within 64B row
  const int arow = lane & 15;
  const int voffQ = (w0 + arow) * 64 + klo;       // + m*1024 imm
  const int voffK = (wv * 64 + arow) * 64 + klo;  // + n*1024 imm (K and V)

  f32x4 acc[4][4];
  #pragma unroll
  for (int m = 0; m < 4; ++m)
    #pragma unroll
    for (int n = 0; n < 4; ++n) acc[m][n] = (f32x4){0.f, 0.f, 0.f, 0.f};

  // scale setup FIRST so the compiler's own vmem waits land before our
  // counted region; SB fences them out of the pipeline
  const float tmp = temp[(slice & 7) >> 1];
  if (tid < 64) sq_l[tid] = tmp / fmaxf(sqrtf(qss[(size_t)slice * HW + w0 + tid]), 1e-12f);
  sk_l[tid] = 1.f / fmaxf(sqrtf(kss[(size_t)slice * HW + tid]), 1e-12f);
  __builtin_amdgcn_sched_barrier(0);

  // ---- phase 1: S = Q K^T, 16 chunk-steps, 4 asm-pinned sets in flight ----
  s16x8 afA[4], bfA[4], afB[4], bfB[4], afC[4], bfC[4], afD[4], bfD[4];
  LOADSET1(afA, bfA, 0)
  LOADSET1(afB, bfB, 1)
  LOADSET1(afC, bfC, 2)
  LOADSET1(afD, bfD, 3)

  #pragma unroll
  for (int g = 0; g < 3; ++g) {
    WAITV(24) MFMA16(afA, bfA, acc) LOADSET1(afA, bfA, 4 * g + 4)
    WAITV(24) MFMA16(afB, bfB, acc) LOADSET1(afB, bfB, 4 * g + 5)
    WAITV(24) MFMA16(afC, bfC, acc) LOADSET1(afC, bfC, 4 * g + 6)
    WAITV(24) MFMA16(afD, bfD, acc) LOADSET1(afD, bfD, 4 * g + 7)
  }
  WAITV(24) MFMA16(afA, bfA, acc)
  WAITV(16) MFMA16(afB, bfB, acc)
  WAITV(8)  MFMA16(afC, bfC, acc)
  WAITV(0)  MFMA16(afD, bfD, acc)
  __syncthreads();  // sq_l/sk_l visible

  // ---- softmax over v (rows w) ----
  float srow[4][4], scol[4];
  #pragma unroll
  for (int m = 0; m < 4; ++m)
    #pragma unroll
    for (int r = 0; r < 4; ++r)
      srow[m][r] = sq_l[m * 16 + ((lane >> 4) << 2) + r];
  #pragma unroll
  for (int n = 0; n < 4; ++n) scol[n] = sk_l[wv * 64 + n * 16 + (lane & 15)];

  float rmax[4][4];
  #pragma unroll
  for (int m = 0; m < 4; ++m)
    #pragma unroll
    for (int r = 0; r < 4; ++r) {
      float mx = -1e30f;
      #pragma unroll
      for (int n = 0; n < 4; ++n) {
        float v = acc[m][n][r] * srow[m][r] * scol[n];
        acc[m][n][r] = v;
        mx = fmaxf(mx, v);
      }
      mx = fmaxf(mx, __shfl_xor(mx, 1));
      mx = fmaxf(mx, __shfl_xor(mx, 2));
      mx = fmaxf(mx, __shfl_xor(mx, 4));
      mx = fmaxf(mx, __shfl_xor(mx, 8));
      rmax[m][r] = mx;
    }
  if ((lane & 15) == 0) {
    #pragma unroll
    for (int m = 0; m < 4; ++m)
      #pragma unroll
      for (int r = 0; r < 4; ++r)
        red_max[(m * 16 + ((lane >> 4) << 2) + r) * 8 + wv] = rmax[m][r];
  }
  __syncthreads();
  if (tid < 64) {
    float mx = red_max[tid * 8];
    #pragma unroll
    for (int g = 1; g < 8; ++g) mx = fmaxf(mx, red_max[tid * 8 + g]);
    red_maxf[tid] = mx;
  }
  __syncthreads();

  float gmax[4][4];
  #pragma unroll
  for (int m = 0; m < 4; ++m)
    #pragma unroll
    for (int r = 0; r < 4; ++r)
      gmax[m][r] = red_maxf[m * 16 + ((lane >> 4) << 2) + r];

  // V prefetch: 4 sets issued now; latency hides under the exp/P-write VALU
  // section and the P-publish barrier's drain (T14)
  s16x8 vfA[4], vfB[4], vfC[4], vfD[4];
  LOADSETV(vfA, 0)
  LOADSETV(vfB, 1)
  LOADSETV(vfC, 2)
  LOADSETV(vfD, 3)

  float rs[4][4];
  #pragma unroll
  for (int m = 0; m < 4; ++m)
    #pragma unroll
    for (int r = 0; r < 4; ++r) rs[m][r] = 0.f;
  #pragma unroll
  for (int m = 0; m < 4; ++m)
    #pragma unroll
    for (int n = 0; n < 4; ++n)
      #pragma unroll
      for (int r = 0; r < 4; ++r) {
        int row = m * 16 + ((lane >> 4) << 2) + r;
        int col = wv * 64 + n * 16 + (lane & 15);
        float pv = __expf(acc[m][n][r] - gmax[m][r]);
        rs[m][r] += pv;
        *(__hip_bfloat16*)(ldsP + row * 1024 + ((col * 2) ^ ((row & 7) << 4))) =
            __float2bfloat16(pv);
      }
  #pragma unroll
  for (int m = 0; m < 4; ++m)
    #pragma unroll
    for (int r = 0; r < 4; ++r) {
      float s = rs[m][r];
      s += __shfl_xor(s, 1);
      s += __shfl_xor(s, 2);
      s += __shfl_xor(s, 4);
      s += __shfl_xor(s, 8);
      if ((lane & 15) == 0)
        red_sum[(m * 16 + ((lane >> 4) << 2) + r) * 8 + wv] = s;
    }
  __syncthreads();  // P + red_sum visible (drains V prefetch too — completed)
  if (tid < 64) {
    float s = 0.f;
    #pragma unroll
    for (int g = 0; g < 8; ++g) s += red_sum[tid * 8 + g];
    rsinv[tid] = 1.f / s;
  }

  // ---- phase 2: O = P V; P from LDS, V via asm-pinned 4-set pipeline ----
  f32x4 acc2[4][4];
  #pragma unroll
  for (int m = 0; m < 4; ++m)
    #pragma unroll
    for (int n = 0; n < 4; ++n) acc2[m][n] = (f32x4){0.f, 0.f, 0.f, 0.f};

  #pragma unroll
  for (int g = 0; g < 3; ++g) {
    WAITV(12) { s16x8 pf[4]; LOADP(pf, 4 * g + 0) MFMA16(pf, vfA, acc2) } LOADSETV(vfA, 4 * g + 4)
    WAITV(12) { s16x8 pf[4]; LOADP(pf, 4 * g + 1) MFMA16(pf, vfB, acc2) } LOADSETV(vfB, 4 * g + 5)
    WAITV(12) { s16x8 pf[4]; LOADP(pf, 4 * g + 2) MFMA16(pf, vfC, acc2) } LOADSETV(vfC, 4 * g + 6)
    WAITV(12) { s16x8 pf[4]; LOADP(pf, 4 * g + 3) MFMA16(pf, vfD, acc2) } LOADSETV(vfD, 4 * g + 7)
  }
  WAITV(12) { s16x8 pf[4]; LOADP(pf, 12) MFMA16(pf, vfA, acc2) }
  WAITV(8)  { s16x8 pf[4]; LOADP(pf, 13) MFMA16(pf, vfB, acc2) }
  WAITV(4)  { s16x8 pf[4]; LOADP(pf, 14) MFMA16(pf, vfC, acc2) }
  WAITV(0)  { s16x8 pf[4]; LOADP(pf, 15) MFMA16(pf, vfD, acc2) }
  __syncthreads();  // P dead; reuse its LDS for O staging

  float rinv[4][4];
  #pragma unroll
  for (int m = 0; m < 4; ++m)
    #pragma unroll
    for (int r = 0; r < 4; ++r)
      rinv[m][r] = rsinv[m * 16 + ((lane >> 4) << 2) + r];

  char* ldsO = ldsP + wv * 8192;  // per-wave [64][128B]
  #pragma unroll
  for (int m = 0; m < 4; ++m)
    #pragma unroll
    for (int n = 0; n < 4; ++n)
      #pragma unroll
      for (int r = 0; r < 4; ++r) {
        int row = m * 16 + ((lane >> 4) << 2) + r;
        int col = n * 16 + (lane & 15);
        *(__hip_bfloat16*)(ldsO + row * 128 + col * 2) =
            __float2bfloat16(acc2[m][n][r] * rinv[m][r]);
      }
  __syncthreads();
  __hip_bfloat16* ob = Obuf + sbase + (size_t)w0 * HW + wv * 64;
  #pragma unroll
  for (int it = 0; it < 8; ++it) {
    int row = it * 8 + (lane >> 3);
    int c = (lane & 7) << 4;
    s16x8 v = *(const s16x8*)(ldsO + row * 128 + c);
    *(s16x8*)((char*)ob + (size_t)row * 1024 + c) = v;
  }
}

// ---------------------------------------------------------------------------
// Kernel 3: out[b][j][h][w] = sum_o wout[j][o] * O[b][o][w][h]
// ---------------------------------------------------------------------------
__global__ __launch_bounds__(256) void proj_kernel(
    const __hip_bfloat16* __restrict__ Obuf, const float* __restrict__ wout,
    float* __restrict__ out)
{
  const int b = blockIdx.y;
  const int t = blockIdx.x;
  const int h0 = (t >> 5) * 64;
  const int w0 = (t & 31) * 16;
  const int tid = threadIdx.x;
  __shared__ float os[8][16][65];
  __shared__ float wo_s[64];
  if (tid < 64) wo_s[tid] = wout[tid];
  {
    int r = tid >> 4;
    int c4 = (tid & 15) * 4;
    #pragma unroll
    for (int o = 0; o < 8; ++o) {
      const __hip_bfloat16* p = Obuf + ((size_t)(b * 8 + o) * HW + w0 + r) * HW + h0 + c4;
      u16x4 v = *(const u16x4*)p;
      #pragma unroll
      for (int i = 0; i < 4; ++i)
        os[o][r][c4 + i] = __uint_as_float((unsigned)v[i] << 16);
    }
  }
  __syncthreads();
  const int w = tid & 15;
  #pragma unroll
  for (int ih = 0; ih < 4; ++ih) {
    int h = ih * 16 + (tid >> 4);
    float ov[8];
    #pragma unroll
    for (int o = 0; o < 8; ++o) ov[o] = os[o][w][h];
    #pragma unroll
    for (int jo = 0; jo < 8; ++jo) {
      float a = 0.f;
      #pragma unroll
      for (int o = 0; o < 8; ++o) a += ov[o] * wo_s[jo * 8 + o];
      out[((size_t)(b * 8 + jo) * HW + h0 + h) * HW + w0 + w] = a;
    }
  }
}

extern "C" void kernel_launch(void* const* d_in, const int* in_sizes, int n_in,
                              void* d_out, int out_size, void* d_ws, size_t ws_size,
                              hipStream_t stream) {
  (void)in_sizes; (void)n_in; (void)out_size; (void)ws_size;
  const float* x    = (const float*)d_in[0];
  const float* wqkv = (const float*)d_in[1];
  const float* wdw  = (const float*)d_in[2];
  const float* wout = (const float*)d_in[3];
  const float* temp = (const float*)d_in[4];
  float* out = (float*)d_out;

  char* ws = (char*)d_ws;
  const size_t plane = (size_t)NSLICE * HW * HW * 2;  // 64 MiB bf16 plane
  __hip_bfloat16* qT = (__hip_bfloat16*)(ws);
  __hip_bfloat16* kT = (__hip_bfloat16*)(ws + plane);
  __hip_bfloat16* vS = (__hip_bfloat16*)(ws + 2 * plane);
  __hip_bfloat16* Ob = (__hip_bfloat16*)(ws + 3 * plane);
  float* qss = (float*)(ws + 4 * plane);
  float* kss = (float*)(ws + 4 * plane + (size_t)NSLICE * HW * 4);

  hipMemsetAsync(qss, 0, 2 * (size_t)NSLICE * HW * 4, stream);
  qkv_fused<<<dim3(256, 16), 256, 0, stream>>>(x, wqkv, wdw, qT, kT, vS, qss, kss);
  hipFuncSetAttribute((const void*)attn_kernel,
                      hipFuncAttributeMaxDynamicSharedMemorySize, ATTN_LDS_SIZE);
  attn_kernel<<<dim3(1024), 512, ATTN_LDS_SIZE, stream>>>(qT, kT, vS, Ob, qss, kss, temp);
  proj_kernel<<<dim3(256, 16), 256, 0, stream>>>(Ob, wout, out);
}

// Round 11
// 322.982 us; speedup vs baseline: 1.2781x; 1.0577x over previous
//
#include <hip/hip_runtime.h>
#include <hip/hip_bf16.h>

typedef __attribute__((ext_vector_type(4))) float f32x4;
typedef __attribute__((ext_vector_type(2))) float f32x2;
typedef __attribute__((ext_vector_type(8))) short s16x8;
typedef __attribute__((ext_vector_type(4))) short s16x4;
typedef __attribute__((ext_vector_type(4))) unsigned short u16x4;

#define HW 512
#define NSLICE 128  // 16 b * 8 ch

// ---------------------------------------------------------------------------
// Kernel 1: fused conv1x1 (8->24ch) + depthwise 3x3 + head-split.
// Chunked layout (R9): [slice][chn][row][32 bf16], row stride 64B.
//   qT/kT: chn = h/32, row = w ; vS: chn = v/32, row = h.  (unchanged)
// ---------------------------------------------------------------------------
__global__ __launch_bounds__(256) void qkv_fused(
    const float* __restrict__ x, const float* __restrict__ wqkv,
    const float* __restrict__ wdw,
    __hip_bfloat16* __restrict__ qT, __hip_bfloat16* __restrict__ kT,
    __hip_bfloat16* __restrict__ vS,
    float* __restrict__ qss, float* __restrict__ kss)
{
  const int b = blockIdx.y;
  const int tile = blockIdx.x;
  const int h0 = (tile >> 4) * 32;
  const int w0 = (tile & 15) * 32;
  const int tid = threadIdx.x;

  __shared__ float ts[4][1156][2];
  __shared__ __hip_bfloat16 ot[8][32][36];
  __shared__ float colsq[4][8][32];
  __shared__ float wq_s[24][8];
  __shared__ float wd_s[24][12];

  if (tid < 192) wq_s[tid >> 3][tid & 7] = wqkv[tid];
  if (tid < 216) wd_s[tid / 9][tid % 9] = wdw[tid];

  float xr[5][8];
  #pragma unroll
  for (int p = 0; p < 5; ++p) {
    int i = tid + p * 256;
    if (i < 1156) {
      int ih = h0 - 1 + i / 34, iw = w0 - 1 + i % 34;
      bool ok = (ih >= 0 && ih < HW && iw >= 0 && iw < HW);
      #pragma unroll
      for (int c = 0; c < 8; ++c) {
        xr[p][c] = ok ? x[((size_t)(b * 8 + c) * HW + ih) * HW + iw] : 0.f;
      }
    }
  }
  __syncthreads();

  const int tw = tid & 31;
  const int th = tid >> 5;
  const int lane = tid & 63;
  const int wv = tid >> 6;

  #pragma unroll
  for (int g = 0; g < 3; ++g) {
    #pragma unroll
    for (int p = 0; p < 5; ++p) {
      int i = tid + p * 256;
      if (i < 1156) {
        #pragma unroll
        for (int op = 0; op < 4; ++op) {
          const int o = g * 8 + op * 2;
          float a0 = 0.f, a1 = 0.f;
          #pragma unroll
          for (int c = 0; c < 8; ++c) {
            a0 += xr[p][c] * wq_s[o][c];
            a1 += xr[p][c] * wq_s[o + 1][c];
          }
          ts[op][i][0] = a0;
          ts[op][i][1] = a1;
        }
      }
    }
    __syncthreads();

    #pragma unroll
    for (int op = 0; op < 4; ++op) {
      const int o = g * 8 + op * 2;
      float w2[6][3][2];
      #pragma unroll
      for (int r = 0; r < 6; ++r)
        #pragma unroll
        for (int c = 0; c < 3; ++c) {
          f32x2 v = *(const f32x2*)&ts[op][(4 * th + r) * 34 + tw + c][0];
          w2[r][c][0] = v[0];
          w2[r][c][1] = v[1];
        }
      float o0[4], o1[4];
      #pragma unroll
      for (int r = 0; r < 4; ++r) { o0[r] = 0.f; o1[r] = 0.f; }
      #pragma unroll
      for (int di = 0; di < 3; ++di)
        #pragma unroll
        for (int dj = 0; dj < 3; ++dj) {
          const float wd0 = wd_s[o][di * 3 + dj];
          const float wd1 = wd_s[o + 1][di * 3 + dj];
          #pragma unroll
          for (int r = 0; r < 4; ++r) {
            o0[r] += w2[r + di][dj][0] * wd0;
            o1[r] += w2[r + di][dj][1] * wd1;
          }
        }
      if (g < 2) {
        float s0 = o0[0] * o0[0] + o0[1] * o0[1] + o0[2] * o0[2] + o0[3] * o0[3];
        float s1 = o1[0] * o1[0] + o1[1] * o1[1] + o1[2] * o1[2] + o1[3] * o1[3];
        s0 += __shfl_xor(s0, 32);
        s1 += __shfl_xor(s1, 32);
        if (lane < 32) {
          colsq[wv][op * 2][tw] = s0;
          colsq[wv][op * 2 + 1][tw] = s1;
        }
        #pragma unroll
        for (int r = 0; r < 4; ++r) {
          ot[op * 2][tw][4 * th + r] = __float2bfloat16(o0[r]);
          ot[op * 2 + 1][tw][4 * th + r] = __float2bfloat16(o1[r]);
        }
      } else {
        #pragma unroll
        for (int r = 0; r < 4; ++r) {
          ot[op * 2][4 * th + r][tw] = __float2bfloat16(o0[r]);
          ot[op * 2 + 1][4 * th + r][tw] = __float2bfloat16(o1[r]);
        }
      }
    }
    __syncthreads();

    {
      const int rr = tid >> 3, cc = tid & 7;
      #pragma unroll
      for (int o = 0; o < 8; ++o) {
        s16x4 v = *(const s16x4*)&ot[o][rr][cc * 4];
        const size_t sb = (size_t)(b * 8 + o) * HW * HW;
        if (g == 0) {
          *(s16x4*)(qT + sb + (size_t)(h0 >> 5) * HW * 32 + (size_t)(w0 + rr) * 32 + cc * 4) = v;
        } else if (g == 1) {
          *(s16x4*)(kT + sb + (size_t)(h0 >> 5) * HW * 32 + (size_t)(w0 + rr) * 32 + cc * 4) = v;
        } else {
          *(s16x4*)(vS + sb + (size_t)(w0 >> 5) * HW * 32 + (size_t)(h0 + rr) * 32 + cc * 4) = v;
        }
      }
    }
    if (g < 2) {
      const int o = tid >> 5, w = tid & 31;
      float s = colsq[0][o][w] + colsq[1][o][w] + colsq[2][o][w] + colsq[3][o][w];
      float* dst = (g == 0 ? qss : kss) + (size_t)(b * 8 + o) * HW + w0 + w;
      atomicAdd(dst, s);
    }
  }
}

// ---------------------------------------------------------------------------
// Kernel 2: per-slice attention. R10 structure + Q-dedup through LDS:
// the 8 waves all consumed identical Q fragments (8x redundant vmem);
// now Q (64 rows x 1KB) is staged once into LDS (region P reuses after
// phase 1), rows padded to 1040B (<=2-way banks, free per m136).
// Phase 1: Q via ds_read_b128 (issued before the counted vmcnt so LDS
// latency hides under the wait) + K via asm-pinned 4-set pipeline
// (vmcnt(12)). Phase 2 unchanged (V has no cross-wave redundancy).
// ---------------------------------------------------------------------------
#define QROW 1040         // 1024B Q row + 16B pad (bank spread)
#define LDS_QP   0        // Q staging 64*1040=66560; P [64][1024] reuses [0,65536)
#define OFF_RMAX 66560    // [64][8] f32
#define OFF_RSUM 68608    // [64][8] f32
#define OFF_RMAXF 70656   // [64] f32
#define OFF_RSINV 70912   // [64] f32
#define OFF_SQ   71168    // [64] f32
#define OFF_SK   71424    // [512] f32
#define ATTN_LDS_SIZE 73472

// 4 fragment loads: base(SGPR pair) + voff(VGPR) + imm row-block offset
#define GL4(D, VOFF, BASE) \
  asm volatile("global_load_dwordx4 %0, %1, %2 offset:0"    : "=v"(D[0]) : "v"(VOFF), "s"(BASE)); \
  asm volatile("global_load_dwordx4 %0, %1, %2 offset:1024" : "=v"(D[1]) : "v"(VOFF), "s"(BASE)); \
  asm volatile("global_load_dwordx4 %0, %1, %2 offset:2048" : "=v"(D[2]) : "v"(VOFF), "s"(BASE)); \
  asm volatile("global_load_dwordx4 %0, %1, %2 offset:3072" : "=v"(D[3]) : "v"(VOFF), "s"(BASE));

#define LOADSETK(BF, CHN) { \
  const char* bk_ = ks + (size_t)(CHN) * 32768; \
  GL4(BF, voffK, bk_) }

#define LOADSETV(VF, CHN) { \
  const char* bv_ = vs + (size_t)(CHN) * 32768; \
  GL4(VF, voffK, bv_) }

#define WAITV(N) \
  asm volatile("s_waitcnt vmcnt(" #N ")"); \
  __builtin_amdgcn_sched_barrier(0);

// Q fragment from LDS (padded rows); ds_reads issued BEFORE the vmcnt wait
#define LDSQ(QF, S) { \
    const int cq_ = (S) * 64 + klo; \
    _Pragma("unroll") for (int m_ = 0; m_ < 4; ++m_) \
      QF[m_] = *(const s16x8*)(ldsQ + (m_ * 16 + arow) * QROW + cq_); }

#define LOADP(AF, S) { \
    const int cbp_ = (S) * 64 + klo; \
    _Pragma("unroll") for (int m_ = 0; m_ < 4; ++m_) { \
      const int row_ = m_ * 16 + arow; \
      AF[m_] = *(const s16x8*)(ldsP + row_ * 1024 + (cbp_ ^ ((row_ & 7) << 4))); } }
#define MFMA16(AF, BF, ACC) { \
    _Pragma("unroll") for (int m_ = 0; m_ < 4; ++m_) \
      _Pragma("unroll") for (int n_ = 0; n_ < 4; ++n_) \
        ACC[m_][n_] = __builtin_amdgcn_mfma_f32_16x16x32_bf16(AF[m_], BF[n_], ACC[m_][n_], 0, 0, 0); }

__global__ __launch_bounds__(512, 1) void attn_kernel(
    const __hip_bfloat16* __restrict__ qT, const __hip_bfloat16* __restrict__ kT,
    const __hip_bfloat16* __restrict__ vS, __hip_bfloat16* __restrict__ Obuf,
    const float* __restrict__ qss, const float* __restrict__ kss,
    const float* __restrict__ temp)
{
  extern __shared__ char smem[];
  char* ldsQ = smem + LDS_QP;
  char* ldsP = smem + LDS_QP;       // P reuses Q region after phase 1
  float* red_max  = (float*)(smem + OFF_RMAX);
  float* red_sum  = (float*)(smem + OFF_RSUM);
  float* red_maxf = (float*)(smem + OFF_RMAXF);
  float* rsinv    = (float*)(smem + OFF_RSINV);
  float* sq_l     = (float*)(smem + OFF_SQ);
  float* sk_l     = (float*)(smem + OFF_SK);

  const int tid = threadIdx.x;
  const int lane = tid & 63;
  const int wv = tid >> 6;
  const int p = blockIdx.x;
  // XCD swizzle: 8 row-blocks of one slice share an XCD (K/V L2 reuse)
  const int slice = (p & 7) + 8 * (p >> 6);
  const int rblk = (p >> 3) & 7;
  const int w0 = rblk * 64;
  const size_t sbase = (size_t)slice * HW * HW;
  const char* qs = (const char*)(qT + sbase);
  const char* ks = (const char*)(kT + sbase);
  const char* vs = (const char*)(vS + sbase);

  const int klo = (lane >> 4) << 4;   // 16B k-slot within 64B row
  const int arow = lane & 15;
  const int voffK = (wv * 64 + arow) * 64 + klo;  // + n*1024 imm (K and V)

  // ---- stage Q tile (rows w0..w0+63, 1KB each) into LDS, padded rows ----
  {
    const int r = tid >> 3;          // 0..63
    const int seg = tid & 7;         // 128B segment of the row
    #pragma unroll
    for (int i = 0; i < 8; ++i) {
      const int chn_i = seg * 2 + (i >> 2);
      s16x8 v = *(const s16x8*)(qs + (size_t)chn_i * 32768 + (size_t)(w0 + r) * 64 + (i & 3) * 16);
      *(s16x8*)(ldsQ + r * QROW + seg * 128 + i * 16) = v;
    }
  }
  const float tmp = temp[(slice & 7) >> 1];
  if (tid < 64) sq_l[tid] = tmp / fmaxf(sqrtf(qss[(size_t)slice * HW + w0 + tid]), 1e-12f);
  sk_l[tid] = 1.f / fmaxf(sqrtf(kss[(size_t)slice * HW + tid]), 1e-12f);
  __syncthreads();  // Q + scales visible

  f32x4 acc[4][4];
  #pragma unroll
  for (int m = 0; m < 4; ++m)
    #pragma unroll
    for (int n = 0; n < 4; ++n) acc[m][n] = (f32x4){0.f, 0.f, 0.f, 0.f};
  __builtin_amdgcn_sched_barrier(0);

  // ---- phase 1: S = Q K^T; Q from LDS, K via 4-set asm pipeline ----
  s16x8 bfA[4], bfB[4], bfC[4], bfD[4];
  LOADSETK(bfA, 0)
  LOADSETK(bfB, 1)
  LOADSETK(bfC, 2)
  LOADSETK(bfD, 3)

  #pragma unroll
  for (int g = 0; g < 3; ++g) {
    { s16x8 qf[4]; LDSQ(qf, 4 * g + 0) WAITV(12) MFMA16(qf, bfA, acc) } LOADSETK(bfA, 4 * g + 4)
    { s16x8 qf[4]; LDSQ(qf, 4 * g + 1) WAITV(12) MFMA16(qf, bfB, acc) } LOADSETK(bfB, 4 * g + 5)
    { s16x8 qf[4]; LDSQ(qf, 4 * g + 2) WAITV(12) MFMA16(qf, bfC, acc) } LOADSETK(bfC, 4 * g + 6)
    { s16x8 qf[4]; LDSQ(qf, 4 * g + 3) WAITV(12) MFMA16(qf, bfD, acc) } LOADSETK(bfD, 4 * g + 7)
  }
  { s16x8 qf[4]; LDSQ(qf, 12) WAITV(12) MFMA16(qf, bfA, acc) }
  { s16x8 qf[4]; LDSQ(qf, 13) WAITV(8)  MFMA16(qf, bfB, acc) }
  { s16x8 qf[4]; LDSQ(qf, 14) WAITV(4)  MFMA16(qf, bfC, acc) }
  { s16x8 qf[4]; LDSQ(qf, 15) WAITV(0)  MFMA16(qf, bfD, acc) }
  __syncthreads();  // all waves done reading Q; P may overwrite the region

  // ---- softmax over v (rows w) ----
  float srow[4][4], scol[4];
  #pragma unroll
  for (int m = 0; m < 4; ++m)
    #pragma unroll
    for (int r = 0; r < 4; ++r)
      srow[m][r] = sq_l[m * 16 + ((lane >> 4) << 2) + r];
  #pragma unroll
  for (int n = 0; n < 4; ++n) scol[n] = sk_l[wv * 64 + n * 16 + (lane & 15)];

  float rmax[4][4];
  #pragma unroll
  for (int m = 0; m < 4; ++m)
    #pragma unroll
    for (int r = 0; r < 4; ++r) {
      float mx = -1e30f;
      #pragma unroll
      for (int n = 0; n < 4; ++n) {
        float v = acc[m][n][r] * srow[m][r] * scol[n];
        acc[m][n][r] = v;
        mx = fmaxf(mx, v);
      }
      mx = fmaxf(mx, __shfl_xor(mx, 1));
      mx = fmaxf(mx, __shfl_xor(mx, 2));
      mx = fmaxf(mx, __shfl_xor(mx, 4));
      mx = fmaxf(mx, __shfl_xor(mx, 8));
      rmax[m][r] = mx;
    }
  if ((lane & 15) == 0) {
    #pragma unroll
    for (int m = 0; m < 4; ++m)
      #pragma unroll
      for (int r = 0; r < 4; ++r)
        red_max[(m * 16 + ((lane >> 4) << 2) + r) * 8 + wv] = rmax[m][r];
  }
  __syncthreads();
  if (tid < 64) {
    float mx = red_max[tid * 8];
    #pragma unroll
    for (int g = 1; g < 8; ++g) mx = fmaxf(mx, red_max[tid * 8 + g]);
    red_maxf[tid] = mx;
  }
  __syncthreads();

  float gmax[4][4];
  #pragma unroll
  for (int m = 0; m < 4; ++m)
    #pragma unroll
    for (int r = 0; r < 4; ++r)
      gmax[m][r] = red_maxf[m * 16 + ((lane >> 4) << 2) + r];

  // V prefetch: 4 sets issued now; latency hides under the exp/P-write VALU
  // section and the P-publish barrier's drain (T14)
  s16x8 vfA[4], vfB[4], vfC[4], vfD[4];
  LOADSETV(vfA, 0)
  LOADSETV(vfB, 1)
  LOADSETV(vfC, 2)
  LOADSETV(vfD, 3)

  float rs[4][4];
  #pragma unroll
  for (int m = 0; m < 4; ++m)
    #pragma unroll
    for (int r = 0; r < 4; ++r) rs[m][r] = 0.f;
  #pragma unroll
  for (int m = 0; m < 4; ++m)
    #pragma unroll
    for (int n = 0; n < 4; ++n)
      #pragma unroll
      for (int r = 0; r < 4; ++r) {
        int row = m * 16 + ((lane >> 4) << 2) + r;
        int col = wv * 64 + n * 16 + (lane & 15);
        float pv = __expf(acc[m][n][r] - gmax[m][r]);
        rs[m][r] += pv;
        *(__hip_bfloat16*)(ldsP + row * 1024 + ((col * 2) ^ ((row & 7) << 4))) =
            __float2bfloat16(pv);
      }
  #pragma unroll
  for (int m = 0; m < 4; ++m)
    #pragma unroll
    for (int r = 0; r < 4; ++r) {
      float s = rs[m][r];
      s += __shfl_xor(s, 1);
      s += __shfl_xor(s, 2);
      s += __shfl_xor(s, 4);
      s += __shfl_xor(s, 8);
      if ((lane & 15) == 0)
        red_sum[(m * 16 + ((lane >> 4) << 2) + r) * 8 + wv] = s;
    }
  __syncthreads();  // P + red_sum visible (V prefetch long since landed)
  if (tid < 64) {
    float s = 0.f;
    #pragma unroll
    for (int g = 0; g < 8; ++g) s += red_sum[tid * 8 + g];
    rsinv[tid] = 1.f / s;
  }

  // ---- phase 2: O = P V; P from LDS, V via asm-pinned 4-set pipeline ----
  f32x4 acc2[4][4];
  #pragma unroll
  for (int m = 0; m < 4; ++m)
    #pragma unroll
    for (int n = 0; n < 4; ++n) acc2[m][n] = (f32x4){0.f, 0.f, 0.f, 0.f};

  #pragma unroll
  for (int g = 0; g < 3; ++g) {
    { s16x8 pf[4]; LOADP(pf, 4 * g + 0) WAITV(12) MFMA16(pf, vfA, acc2) } LOADSETV(vfA, 4 * g + 4)
    { s16x8 pf[4]; LOADP(pf, 4 * g + 1) WAITV(12) MFMA16(pf, vfB, acc2) } LOADSETV(vfB, 4 * g + 5)
    { s16x8 pf[4]; LOADP(pf, 4 * g + 2) WAITV(12) MFMA16(pf, vfC, acc2) } LOADSETV(vfC, 4 * g + 6)
    { s16x8 pf[4]; LOADP(pf, 4 * g + 3) WAITV(12) MFMA16(pf, vfD, acc2) } LOADSETV(vfD, 4 * g + 7)
  }
  { s16x8 pf[4]; LOADP(pf, 12) WAITV(12) MFMA16(pf, vfA, acc2) }
  { s16x8 pf[4]; LOADP(pf, 13) WAITV(8)  MFMA16(pf, vfB, acc2) }
  { s16x8 pf[4]; LOADP(pf, 14) WAITV(4)  MFMA16(pf, vfC, acc2) }
  { s16x8 pf[4]; LOADP(pf, 15) WAITV(0)  MFMA16(pf, vfD, acc2) }
  __syncthreads();  // P dead; reuse its LDS for O staging

  float rinv[4][4];
  #pragma unroll
  for (int m = 0; m < 4; ++m)
    #pragma unroll
    for (int r = 0; r < 4; ++r)
      rinv[m][r] = rsinv[m * 16 + ((lane >> 4) << 2) + r];

  char* ldsO = ldsP + wv * 8192;  // per-wave [64][128B]
  #pragma unroll
  for (int m = 0; m < 4; ++m)
    #pragma unroll
    for (int n = 0; n < 4; ++n)
      #pragma unroll
      for (int r = 0; r < 4; ++r) {
        int row = m * 16 + ((lane >> 4) << 2) + r;
        int col = n * 16 + (lane & 15);
        *(__hip_bfloat16*)(ldsO + row * 128 + col * 2) =
            __float2bfloat16(acc2[m][n][r] * rinv[m][r]);
      }
  __syncthreads();
  __hip_bfloat16* ob = Obuf + sbase + (size_t)w0 * HW + wv * 64;
  #pragma unroll
  for (int it = 0; it < 8; ++it) {
    int row = it * 8 + (lane >> 3);
    int c = (lane & 7) << 4;
    s16x8 v = *(const s16x8*)(ldsO + row * 128 + c);
    *(s16x8*)((char*)ob + (size_t)row * 1024 + c) = v;
  }
}

// ---------------------------------------------------------------------------
// Kernel 3: out[b][j][h][w] = sum_o wout[j][o] * O[b][o][w][h]
// ---------------------------------------------------------------------------
__global__ __launch_bounds__(256) void proj_kernel(
    const __hip_bfloat16* __restrict__ Obuf, const float* __restrict__ wout,
    float* __restrict__ out)
{
  const int b = blockIdx.y;
  const int t = blockIdx.x;
  const int h0 = (t >> 5) * 64;
  const int w0 = (t & 31) * 16;
  const int tid = threadIdx.x;
  __shared__ float os[8][16][65];
  __shared__ float wo_s[64];
  if (tid < 64) wo_s[tid] = wout[tid];
  {
    int r = tid >> 4;
    int c4 = (tid & 15) * 4;
    #pragma unroll
    for (int o = 0; o < 8; ++o) {
      const __hip_bfloat16* p = Obuf + ((size_t)(b * 8 + o) * HW + w0 + r) * HW + h0 + c4;
      u16x4 v = *(const u16x4*)p;
      #pragma unroll
      for (int i = 0; i < 4; ++i)
        os[o][r][c4 + i] = __uint_as_float((unsigned)v[i] << 16);
    }
  }
  __syncthreads();
  const int w = tid & 15;
  #pragma unroll
  for (int ih = 0; ih < 4; ++ih) {
    int h = ih * 16 + (tid >> 4);
    float ov[8];
    #pragma unroll
    for (int o = 0; o < 8; ++o) ov[o] = os[o][w][h];
    #pragma unroll
    for (int jo = 0; jo < 8; ++jo) {
      float a = 0.f;
      #pragma unroll
      for (int o = 0; o < 8; ++o) a += ov[o] * wo_s[jo * 8 + o];
      out[((size_t)(b * 8 + jo) * HW + h0 + h) * HW + w0 + w] = a;
    }
  }
}

extern "C" void kernel_launch(void* const* d_in, const int* in_sizes, int n_in,
                              void* d_out, int out_size, void* d_ws, size_t ws_size,
                              hipStream_t stream) {
  (void)in_sizes; (void)n_in; (void)out_size; (void)ws_size;
  const float* x    = (const float*)d_in[0];
  const float* wqkv = (const float*)d_in[1];
  const float* wdw  = (const float*)d_in[2];
  const float* wout = (const float*)d_in[3];
  const float* temp = (const float*)d_in[4];
  float* out = (float*)d_out;

  char* ws = (char*)d_ws;
  const size_t plane = (size_t)NSLICE * HW * HW * 2;  // 64 MiB bf16 plane
  __hip_bfloat16* qT = (__hip_bfloat16*)(ws);
  __hip_bfloat16* kT = (__hip_bfloat16*)(ws + plane);
  __hip_bfloat16* vS = (__hip_bfloat16*)(ws + 2 * plane);
  __hip_bfloat16* Ob = (__hip_bfloat16*)(ws + 3 * plane);
  float* qss = (float*)(ws + 4 * plane);
  float* kss = (float*)(ws + 4 * plane + (size_t)NSLICE * HW * 4);

  hipMemsetAsync(qss, 0, 2 * (size_t)NSLICE * HW * 4, stream);
  qkv_fused<<<dim3(256, 16), 256, 0, stream>>>(x, wqkv, wdw, qT, kT, vS, qss, kss);
  hipFuncSetAttribute((const void*)attn_kernel,
                      hipFuncAttributeMaxDynamicSharedMemorySize, ATTN_LDS_SIZE);
  attn_kernel<<<dim3(1024), 512, ATTN_LDS_SIZE, stream>>>(qT, kT, vS, Ob, qss, kss, temp);
  proj_kernel<<<dim3(256, 16), 256, 0, stream>>>(Ob, wout, out);
}